// Round 9
// baseline (476.117 us; speedup 1.0000x reference)
//
#include <hip/hip_runtime.h>

#define U 4096
#define S 8192
#define D 32
#define NUM_REGIONS 128
#define GA 0.1f

#define WU 16      // users per block (MFMA N axis)
#define WI 1024    // items per block (4 waves x 256)
#define THREADS 256
#define LCAP 256   // max users per region (expected ~32)
#define NBLK ((U / WU) * (S / WI))   // 2048 blocks

typedef short          frag8_t __attribute__((ext_vector_type(8)));  // 8 bf16 bits
typedef unsigned short u16x8_t __attribute__((ext_vector_type(8)));
typedef float          fx4_t   __attribute__((ext_vector_type(4)));

// split fp32x8 into hi/lo bf16 fragments: v = hi + lo to ~16 mantissa bits.
__device__ inline void split8(const float4 a, const float4 b, frag8_t& hi, frag8_t& lo) {
    u16x8_t h, l;
    float vv[8] = {a.x, a.y, a.z, a.w, b.x, b.y, b.z, b.w};
    #pragma unroll
    for (int j = 0; j < 8; j++) {
        unsigned bits = __float_as_uint(vv[j]);
        h[j] = (unsigned short)(bits >> 16);
        float r = vv[j] - __uint_as_float(bits & 0xFFFF0000u);
        l[j] = (unsigned short)(__float_as_uint(r) >> 16);
    }
    hi = __builtin_bit_cast(frag8_t, h);
    lo = __builtin_bit_cast(frag8_t, l);
}

// ---------------- fused kernel: MFMA masked-MSE + region loss ----------------
// Session invariant: every structure (scalar or MFMA, occ 20-68%, VGPR 32-108)
// delivered the 402 MB stream at ~2.7 TB/s => Little's-law latency ceiling
// (~5 outstanding 16B loads/wave x ~400cyc = ~2.5 TB/s), not a pipe limit
// (round 8: VALU 8%, Mfma 1.6%, HBM 27%, all idle, dur unchanged).
// Fix: BATCH 4 t-steps of loads (12 stream + 8 item dwordx4 back-to-back,
// 320 B in flight per lane) before any use -> ~4x bytes in flight.
// MFMA math identical to round 8 (passed, absmax 0.0).

__global__ __launch_bounds__(THREADS) void fused_kernel(
    const float* __restrict__ user_emb,
    const float* __restrict__ item_emb,
    const int* __restrict__ train_mask,
    const float* __restrict__ true_qos,
    const float* __restrict__ us_lossweight,
    const int* __restrict__ region_index,
    float* __restrict__ loss_accum,
    float* __restrict__ rl_accum,
    unsigned* __restrict__ done_cnt,
    float* __restrict__ out) {
    __shared__ float wp[THREADS / 64];
    __shared__ int   ulist[LCAP];
    __shared__ int   ucnt;
    __shared__ float part[8][D];
    __shared__ float redsum[D];

    const int lane = threadIdx.x & 63;
    const int wid  = threadIdx.x >> 6;
    const int n16  = lane & 15;     // user offset (N) / item row offset (M)
    const int g    = lane >> 4;     // k-group and C-quad group
    const int kb   = g * 8;         // this lane's k slice

    const int ub      = blockIdx.x * WU;
    const int it_base = blockIdx.y * WI + wid * 256;   // this wave's 256 items

    // user B-fragment: 8 consecutive dims of one user row, loaded once
    frag8_t uh, ul;
    {
        const float* up = user_emb + (ub + n16) * D + kb;
        split8(*(const float4*)up, *(const float4*)(up + 4), uh, ul);
    }

    const unsigned soff = (unsigned)(ub + n16) * S + it_base + g * 4;
    const int*   mp  = train_mask    + soff;
    const float* qp  = true_qos      + soff;
    const float* wtp = us_lossweight + soff;
    const float* ip  = item_emb + (it_base + n16) * D + kb;

    float acc = 0.0f;
    #pragma unroll 1
    for (int tb = 0; tb < 4; tb++) {           // 4 batches x 4 t-steps
        // ---- issue ALL 20 loads back-to-back (320 B in flight/lane) ----
        int4   m4[4]; float4 q4[4], w4[4], ia[4], ib[4];
        #pragma unroll
        for (int tt = 0; tt < 4; tt++) {
            const int t = tb * 4 + tt;
            m4[tt] = *(const int4*)(mp + t * 16);
            q4[tt] = *(const float4*)(qp + t * 16);
            w4[tt] = *(const float4*)(wtp + t * 16);
            ia[tt] = *(const float4*)(ip + t * 16 * D);
            ib[tt] = *(const float4*)(ip + t * 16 * D + 4);
        }
        // ---- consume ----
        #pragma unroll
        for (int tt = 0; tt < 4; tt++) {
            frag8_t ih, il;
            split8(ia[tt], ib[tt], ih, il);
            fx4_t c = {0.0f, 0.0f, 0.0f, 0.0f};
            c = __builtin_amdgcn_mfma_f32_16x16x32_bf16(ih, uh, c, 0, 0, 0);
            c = __builtin_amdgcn_mfma_f32_16x16x32_bf16(il, uh, c, 0, 0, 0);
            c = __builtin_amdgcn_mfma_f32_16x16x32_bf16(ih, ul, c, 0, 0, 0);
            // c[r] = pre_qos[user=ub+n16][item = it_base + t*16 + g*4 + r]
            float p0 = c[0] * (float)m4[tt].x; float e0 = p0 - q4[tt].x; acc += w4[tt].x * e0 * e0;
            float p1 = c[1] * (float)m4[tt].y; float e1 = p1 - q4[tt].y; acc += w4[tt].y * e1 * e1;
            float p2 = c[2] * (float)m4[tt].z; float e2 = p2 - q4[tt].z; acc += w4[tt].z * e2 * e2;
            float p3 = c[3] * (float)m4[tt].w; float e3 = p3 - q4[tt].w; acc += w4[tt].w * e3 * e3;
        }
    }

    // wave64 reduce + one atomic per block
    #pragma unroll
    for (int off = 32; off > 0; off >>= 1) acc += __shfl_down(acc, off, 64);
    if (lane == 0) wp[wid] = acc;
    __syncthreads();
    if (threadIdx.x == 0)
        atomicAdd(loss_accum, wp[0] + wp[1] + wp[2] + wp[3]);

    // ---- region duty: blocks (r, 0) for r < NUM_REGIONS handle region r ----
    if (blockIdx.y == 0 && blockIdx.x < NUM_REGIONS) {
        const int r = blockIdx.x;

        __syncthreads();                 // wp reads above complete before reuse
        if (threadIdx.x == 0) ucnt = 0;
        __syncthreads();

        // parallel scan straight from global (region_index is 16 KB, L2-resident)
        for (int u = threadIdx.x; u < U; u += 256) {
            if (region_index[u] == r) {
                int p = atomicAdd(&ucnt, 1);
                if (p < LCAP) ulist[p] = u;
            }
        }
        __syncthreads();

        const int n = min(ucnt, LCAP);
        const int d = threadIdx.x & (D - 1);
        const int w8 = threadIdx.x >> 5;

        float psum = 0.0f;
        for (int i = w8; i < n; i += 8)
            psum += user_emb[ulist[i] * D + d];
        part[w8][d] = psum;
        __syncthreads();
        if (w8 == 0) {
            float sum = 0.0f;
            #pragma unroll
            for (int i = 0; i < 8; i++) sum += part[i][d];
            redsum[d] = sum;
        }
        __syncthreads();

        float racc = 0.0f;
        if (n > 1) {
            const float inv = 1.0f / (float)(n - 1);
            const float sd = redsum[d];
            for (int i = w8; i < n; i += 8) {
                float e = user_emb[ulist[i] * D + d];
                racc += fabsf(e - (sd - e) * inv);
            }
        }

        #pragma unroll
        for (int off = 32; off > 0; off >>= 1) racc += __shfl_down(racc, off, 64);
        if (lane == 0) wp[wid] = racc;
        __syncthreads();
        if (threadIdx.x == 0)
            atomicAdd(rl_accum, wp[0] + wp[1] + wp[2] + wp[3]);
    }

    // ---- inline finalize: last block to finish writes the output ----
    // (saves one dispatch; dispatch overhead has looked worth ~15us each)
    if (threadIdx.x == 0) {
        __threadfence();                         // my atomics visible device-wide
        unsigned prev = atomicAdd(done_cnt, 1u);
        if (prev == NBLK - 1) {
            float l = atomicAdd(loss_accum, 0.0f);  // coherent reads
            float r = atomicAdd(rl_accum, 0.0f);
            out[0] = l + GA * r;
        }
    }
}

extern "C" void kernel_launch(void* const* d_in, const int* in_sizes, int n_in,
                              void* d_out, int out_size, void* d_ws, size_t ws_size,
                              hipStream_t stream) {
    const float* user_emb      = (const float*)d_in[0];
    const float* item_emb      = (const float*)d_in[1];
    const int*   train_mask    = (const int*)d_in[2];
    const float* true_qos      = (const float*)d_in[3];
    const float* us_lossweight = (const float*)d_in[4];
    const int*   region_index  = (const int*)d_in[5];
    float* out = (float*)d_out;

    float*    ws       = (float*)d_ws;
    float*    loss_acc = ws;                   // 1 float
    float*    rl_acc   = ws + 1;               // 1 float
    unsigned* done_cnt = (unsigned*)(ws + 2);  // 1 u32
    hipMemsetAsync(d_ws, 0, 3 * sizeof(float), stream);

    dim3 grid(U / WU, S / WI);     // (256, 8); (r<128, 0) also do region duty
    fused_kernel<<<grid, THREADS, 0, stream>>>(
        user_emb, item_emb, train_mask, true_qos, us_lossweight, region_index,
        loss_acc, rl_acc, done_cnt, out);
}

// Round 10
// 371.039 us; speedup vs baseline: 1.2832x; 1.2832x over previous
//
#include <hip/hip_runtime.h>

#define U 4096
#define S 8192
#define D 32
#define NUM_REGIONS 128
#define GA 0.1f

#define WU 16      // users per block (MFMA N axis)
#define WI 512     // items per block (4 waves x 128) -> 4096 blocks, 2x capacity
#define THREADS 256
#define LCAP 256   // max users per region (expected ~32)

typedef short          frag8_t __attribute__((ext_vector_type(8)));  // 8 bf16 bits
typedef unsigned short u16x8_t __attribute__((ext_vector_type(8)));
typedef float          fx4_t   __attribute__((ext_vector_type(4)));

// split fp32x8 into hi/lo bf16 fragments: v = hi + lo to ~16 mantissa bits.
__device__ inline void split8(const float4 a, const float4 b, frag8_t& hi, frag8_t& lo) {
    u16x8_t h, l;
    float vv[8] = {a.x, a.y, a.z, a.w, b.x, b.y, b.z, b.w};
    #pragma unroll
    for (int j = 0; j < 8; j++) {
        unsigned bits = __float_as_uint(vv[j]);
        h[j] = (unsigned short)(bits >> 16);
        float r = vv[j] - __uint_as_float(bits & 0xFFFF0000u);
        l[j] = (unsigned short)(__float_as_uint(r) >> 16);
    }
    hi = __builtin_bit_cast(frag8_t, h);
    lo = __builtin_bit_cast(frag8_t, l);
}

// ---------------- fused kernel: MFMA masked-MSE + region loss ----------------
// Little's-law ceiling: round 8 = ~20 waves/CU x ~5x16B in flight / ~400cyc
// = 2.5 TB/s (matches). Round 9's batch-x4 needed 80 VGPRs, got 68 ->
// allocator reuse serialized the batch (occ 28%, 1.6 TB/s). This round:
// batch-x2 with NAMED scalars (10 float4 = 40 regs, fits the 64-reg/8-wave
// budget) + 2x blocks (WI=512) so scheduler backfill holds occupancy up.

__global__ __launch_bounds__(THREADS) void fused_kernel(
    const float* __restrict__ user_emb,
    const float* __restrict__ item_emb,
    const int* __restrict__ train_mask,
    const float* __restrict__ true_qos,
    const float* __restrict__ us_lossweight,
    const int* __restrict__ region_index,
    float* __restrict__ loss_accum,
    float* __restrict__ rl_accum) {
    __shared__ float wp[THREADS / 64];
    __shared__ int   ulist[LCAP];
    __shared__ int   ucnt;
    __shared__ float part[8][D];
    __shared__ float redsum[D];

    const int lane = threadIdx.x & 63;
    const int wid  = threadIdx.x >> 6;
    const int n16  = lane & 15;     // user offset (N) / item row offset (M)
    const int g    = lane >> 4;     // k-group and C-quad group
    const int kb   = g * 8;         // this lane's k slice

    const int ub      = blockIdx.x * WU;
    const int it_base = blockIdx.y * WI + wid * 128;   // this wave's 128 items

    // user B-fragment: 8 consecutive dims of one user row, loaded once
    frag8_t uh, ul;
    {
        const float* up = user_emb + (ub + n16) * D + kb;
        split8(*(const float4*)up, *(const float4*)(up + 4), uh, ul);
    }

    const unsigned soff = (unsigned)(ub + n16) * S + it_base + g * 4;
    const int*   mp  = train_mask    + soff;
    const float* qp  = true_qos      + soff;
    const float* wtp = us_lossweight + soff;
    const float* ip  = item_emb + (it_base + n16) * D + kb;

    float acc = 0.0f;
    #pragma unroll 1
    for (int tb = 0; tb < 4; tb++) {       // 4 batches x 2 t-steps (8 tiles)
        const int t0 = tb * 2, t1 = tb * 2 + 1;
        // ---- issue all 10 loads back-to-back (160 B in flight/lane) ----
        int4   m4a = *(const int4*)(mp + t0 * 16);
        float4 q4a = *(const float4*)(qp + t0 * 16);
        float4 w4a = *(const float4*)(wtp + t0 * 16);
        float4 iaa = *(const float4*)(ip + t0 * 16 * D);
        float4 iba = *(const float4*)(ip + t0 * 16 * D + 4);
        int4   m4b = *(const int4*)(mp + t1 * 16);
        float4 q4b = *(const float4*)(qp + t1 * 16);
        float4 w4b = *(const float4*)(wtp + t1 * 16);
        float4 iab = *(const float4*)(ip + t1 * 16 * D);
        float4 ibb = *(const float4*)(ip + t1 * 16 * D + 4);

        // ---- consume t0 ----
        {
            frag8_t ih, il;
            split8(iaa, iba, ih, il);
            fx4_t c = {0.0f, 0.0f, 0.0f, 0.0f};
            c = __builtin_amdgcn_mfma_f32_16x16x32_bf16(ih, uh, c, 0, 0, 0);
            c = __builtin_amdgcn_mfma_f32_16x16x32_bf16(il, uh, c, 0, 0, 0);
            c = __builtin_amdgcn_mfma_f32_16x16x32_bf16(ih, ul, c, 0, 0, 0);
            float p0 = c[0] * (float)m4a.x; float e0 = p0 - q4a.x; acc += w4a.x * e0 * e0;
            float p1 = c[1] * (float)m4a.y; float e1 = p1 - q4a.y; acc += w4a.y * e1 * e1;
            float p2 = c[2] * (float)m4a.z; float e2 = p2 - q4a.z; acc += w4a.z * e2 * e2;
            float p3 = c[3] * (float)m4a.w; float e3 = p3 - q4a.w; acc += w4a.w * e3 * e3;
        }
        // ---- consume t1 ----
        {
            frag8_t ih, il;
            split8(iab, ibb, ih, il);
            fx4_t c = {0.0f, 0.0f, 0.0f, 0.0f};
            c = __builtin_amdgcn_mfma_f32_16x16x32_bf16(ih, uh, c, 0, 0, 0);
            c = __builtin_amdgcn_mfma_f32_16x16x32_bf16(il, uh, c, 0, 0, 0);
            c = __builtin_amdgcn_mfma_f32_16x16x32_bf16(ih, ul, c, 0, 0, 0);
            float p0 = c[0] * (float)m4b.x; float e0 = p0 - q4b.x; acc += w4b.x * e0 * e0;
            float p1 = c[1] * (float)m4b.y; float e1 = p1 - q4b.y; acc += w4b.y * e1 * e1;
            float p2 = c[2] * (float)m4b.z; float e2 = p2 - q4b.z; acc += w4b.z * e2 * e2;
            float p3 = c[3] * (float)m4b.w; float e3 = p3 - q4b.w; acc += w4b.w * e3 * e3;
        }
    }

    // wave64 reduce + one atomic per block
    #pragma unroll
    for (int off = 32; off > 0; off >>= 1) acc += __shfl_down(acc, off, 64);
    if (lane == 0) wp[wid] = acc;
    __syncthreads();
    if (threadIdx.x == 0)
        atomicAdd(loss_accum, wp[0] + wp[1] + wp[2] + wp[3]);

    // ---- region duty: blocks (r, 0) for r < NUM_REGIONS handle region r ----
    if (blockIdx.y != 0 || blockIdx.x >= NUM_REGIONS) return;
    const int r = blockIdx.x;

    __syncthreads();                 // wp reads above complete before reuse
    if (threadIdx.x == 0) ucnt = 0;
    __syncthreads();

    // parallel scan straight from global (region_index is 16 KB, L2-resident)
    for (int u = threadIdx.x; u < U; u += 256) {
        if (region_index[u] == r) {
            int p = atomicAdd(&ucnt, 1);
            if (p < LCAP) ulist[p] = u;
        }
    }
    __syncthreads();

    const int n = min(ucnt, LCAP);
    const int d = threadIdx.x & (D - 1);      // dim 0..31
    const int w8 = threadIdx.x >> 5;          // list stripe 0..7

    // pass 1: region sum over the compact list (~4 iters per stripe)
    float psum = 0.0f;
    for (int i = w8; i < n; i += 8)
        psum += user_emb[ulist[i] * D + d];
    part[w8][d] = psum;
    __syncthreads();
    if (w8 == 0) {
        float sum = 0.0f;
        #pragma unroll
        for (int i = 0; i < 8; i++) sum += part[i][d];
        redsum[d] = sum;
    }
    __syncthreads();

    // pass 2: leave-one-out deviation over the list
    float racc = 0.0f;
    if (n > 1) {
        const float inv = 1.0f / (float)(n - 1);
        const float sd = redsum[d];
        for (int i = w8; i < n; i += 8) {
            float e = user_emb[ulist[i] * D + d];
            racc += fabsf(e - (sd - e) * inv);
        }
    }

    #pragma unroll
    for (int off = 32; off > 0; off >>= 1) racc += __shfl_down(racc, off, 64);
    if (lane == 0) wp[wid] = racc;
    __syncthreads();
    if (threadIdx.x == 0)
        atomicAdd(rl_accum, wp[0] + wp[1] + wp[2] + wp[3]);
}

__global__ void finalize_kernel(const float* __restrict__ loss_acc,
                                const float* __restrict__ rl_acc,
                                float* __restrict__ out) {
    out[0] = loss_acc[0] + GA * rl_acc[0];
}

extern "C" void kernel_launch(void* const* d_in, const int* in_sizes, int n_in,
                              void* d_out, int out_size, void* d_ws, size_t ws_size,
                              hipStream_t stream) {
    const float* user_emb      = (const float*)d_in[0];
    const float* item_emb      = (const float*)d_in[1];
    const int*   train_mask    = (const int*)d_in[2];
    const float* true_qos      = (const float*)d_in[3];
    const float* us_lossweight = (const float*)d_in[4];
    const int*   region_index  = (const int*)d_in[5];
    float* out = (float*)d_out;

    float* ws       = (float*)d_ws;
    float* loss_acc = ws;          // 1
    float* rl_acc   = ws + 1;      // 1
    hipMemsetAsync(d_ws, 0, 2 * sizeof(float), stream);

    dim3 grid(U / WU, S / WI);     // (256, 16); (r<128, 0) also do region duty
    fused_kernel<<<grid, THREADS, 0, stream>>>(
        user_emb, item_emb, train_mask, true_qos, us_lossweight, region_index,
        loss_acc, rl_acc);

    finalize_kernel<<<1, 1, 0, stream>>>(loss_acc, rl_acc, out);
}